// Round 4
// baseline (43.553 us; speedup 1.0000x reference)
//
#include <hip/hip_runtime.h>

// Problem constants (match reference setup_inputs)
constexpr int B_CONST = 4096;
constexpr int P_CONST = 460;   // pixel pairs per row
constexpr int C_CONST = 10;    // classes
constexpr int PIX     = 3072;  // 3*32*32
constexpr int ROW_OUT = P_CONST * 2 * C_CONST;        // 9200 floats per row
constexpr int ROW_F4  = ROW_OUT / 4;                  // 2300 float4 per row

// clang-native vectors (accepted by __builtin_nontemporal_*)
typedef float f32x4 __attribute__((ext_vector_type(4)));
typedef int   i32x4 __attribute__((ext_vector_type(4)));
typedef int   i32x2 __attribute__((ext_vector_type(2)));

// Closed form of the reference circuit (exact trig identities):
//   z0[c] = cos(x0)*cos(theta_c) - sin(x0)*sin(x1)*sin(theta_c)
//   z1    = cos(x0)*cos(x1)                  (theta-independent)
//   q     = (z + 1)/2
__global__ __launch_bounds__(256)
void quantum_pair_kernel(const float* __restrict__ x,     // [B, 3072]
                         const int*   __restrict__ pidx,  // [B, P, 2]
                         const float* __restrict__ theta, // [C]
                         float* __restrict__ out)         // [B, P, 2, C]
{
    __shared__ float xs[PIX];
    __shared__ i32x2 ps[P_CONST];
    __shared__ float hc[2 * C_CONST];   // 0.5*cos(theta) (idx<10), dummy above
    __shared__ float hs[2 * C_CONST];   // 0.5*sin(theta)

    const int b   = blockIdx.x;
    const int tid = threadIdx.x;

    // --- stage x row into LDS (3072 floats = 768 float4, 3 per thread), nt loads ---
    const f32x4* xrow4 = reinterpret_cast<const f32x4*>(x + (size_t)b * PIX);
    f32x4* xs4 = reinterpret_cast<f32x4*>(xs);
#pragma unroll
    for (int i = 0; i < 3; ++i) {
        const int idx = tid + i * 256;
        xs4[idx] = __builtin_nontemporal_load(&xrow4[idx]);
    }

    // --- stage pair row into LDS: 460 int2 = 230 int4, coalesced, nt loads ---
    const i32x4* prow4 = reinterpret_cast<const i32x4*>(pidx + (size_t)b * (P_CONST * 2));
    i32x4* ps4 = reinterpret_cast<i32x4*>(ps);
    if (tid < P_CONST / 2) {
        ps4[tid] = __builtin_nontemporal_load(&prow4[tid]);
    }

    // per-class constants (slots 10..19 are dummies so w-indexing stays in-bounds)
    if (tid < 2 * C_CONST) {
        const float t = (tid < C_CONST) ? theta[tid] : 0.0f;
        hc[tid] = 0.5f * __cosf(t);
        hs[tid] = 0.5f * __sinf(t);
    }
    __syncthreads();

    f32x4* orow4 = reinterpret_cast<f32x4*>(out + (size_t)b * (size_t)ROW_OUT);

    // thread -> output float4 index: fully coalesced streaming stores
#pragma unroll
    for (int it = 0; it < 9; ++it) {
        const int f = tid + it * 256;
        if (f < ROW_F4) {
            const int p    = f / 5;          // pair index (magic-mul)
            const int slot = f - p * 5;      // which float4 within the 20 outputs

            const i32x2 ij = ps[p];
            const float x0 = xs[ij.x];
            const float x1 = xs[ij.y];

            const float sx0 = __sinf(x0);
            const float cx0 = __cosf(x0);
            const float sx1 = __sinf(x1);
            const float cx1 = __cosf(x1);

            const float sxx = sx0 * sx1;
            const float q1v = fmaf(cx0, 0.5f * cx1, 0.5f);  // (cos(x0)cos(x1)+1)/2

            const int w0 = slot * 4;
            f32x4 rr;
#pragma unroll
            for (int j = 0; j < 4; ++j) {
                const int w = w0 + j;  // word within the pair's 20 outputs
                const float q0 = fmaf(cx0, hc[w], fmaf(-sxx, hs[w], 0.5f));
                rr[j] = (w < C_CONST) ? q0 : q1v;
            }
            __builtin_nontemporal_store(rr, &orow4[f]);
        }
    }
}

extern "C" void kernel_launch(void* const* d_in, const int* in_sizes, int n_in,
                              void* d_out, int out_size, void* d_ws, size_t ws_size,
                              hipStream_t stream) {
    const float* x     = (const float*)d_in[0];
    const int*   pidx  = (const int*)d_in[1];
    const float* theta = (const float*)d_in[2];
    float* out = (float*)d_out;

    quantum_pair_kernel<<<B_CONST, 256, 0, stream>>>(x, pidx, theta, out);
}

// Round 5
// 37.529 us; speedup vs baseline: 1.1605x; 1.1605x over previous
//
#include <hip/hip_runtime.h>

// Problem constants (match reference setup_inputs)
constexpr int B_CONST = 4096;
constexpr int P_CONST = 460;   // pixel pairs per row
constexpr int C_CONST = 10;    // classes
constexpr int PIX     = 3072;  // 3*32*32
constexpr int ROW_OUT = P_CONST * 2 * C_CONST;        // 9200 floats per row
constexpr int ROW_F4  = ROW_OUT / 4;                  // 2300 float4 per row

// Closed form of the reference circuit (exact trig identities):
//   z0[c] = cos(x0)*cos(theta_c) - sin(x0)*sin(x1)*sin(theta_c)
//   z1    = cos(x0)*cos(x1)                  (theta-independent)
//   q     = (z + 1)/2
__global__ __launch_bounds__(256)
void quantum_pair_kernel(const float* __restrict__ x,     // [B, 3072]
                         const int*   __restrict__ pidx,  // [B, P, 2]
                         const float* __restrict__ theta, // [C]
                         float* __restrict__ out)         // [B, P, 2, C]
{
    __shared__ float xs[PIX];
    __shared__ int2  ps[P_CONST];
    __shared__ float hc[2 * C_CONST];   // 0.5*cos(theta) (idx<10), dummy above
    __shared__ float hs[2 * C_CONST];   // 0.5*sin(theta)

    const int b   = blockIdx.x;
    const int tid = threadIdx.x;

    // --- stage x row into LDS (3072 floats = 768 float4, 3 per thread) ---
    const float4* xrow4 = reinterpret_cast<const float4*>(x + (size_t)b * PIX);
    float4* xs4 = reinterpret_cast<float4*>(xs);
#pragma unroll
    for (int i = 0; i < 3; ++i) {
        const int idx = tid + i * 256;
        xs4[idx] = xrow4[idx];
    }

    // --- stage pair row into LDS: 460 int2 = 230 int4, coalesced ---
    const int4* prow4 = reinterpret_cast<const int4*>(pidx + (size_t)b * (P_CONST * 2));
    int4* ps4 = reinterpret_cast<int4*>(ps);
    if (tid < P_CONST / 2) {
        ps4[tid] = prow4[tid];
    }

    // per-class constants (slots 10..19 are dummies so w-indexing stays in-bounds)
    if (tid < 2 * C_CONST) {
        const float t = (tid < C_CONST) ? theta[tid] : 0.0f;
        hc[tid] = 0.5f * __cosf(t);
        hs[tid] = 0.5f * __sinf(t);
    }
    __syncthreads();

    float4* orow4 = reinterpret_cast<float4*>(out + (size_t)b * (size_t)ROW_OUT);

    // thread -> output float4 index: fully coalesced stores
#pragma unroll
    for (int it = 0; it < 9; ++it) {
        const int f = tid + it * 256;
        if (f < ROW_F4) {
            const int p    = f / 5;          // pair index (magic-mul)
            const int slot = f - p * 5;      // which float4 within the 20 outputs

            const int2 ij = ps[p];
            const float x0 = xs[ij.x];
            const float x1 = xs[ij.y];

            const float sx0 = __sinf(x0);
            const float cx0 = __cosf(x0);
            const float sx1 = __sinf(x1);
            const float cx1 = __cosf(x1);

            const float sxx = sx0 * sx1;
            const float q1v = fmaf(cx0, 0.5f * cx1, 0.5f);  // (cos(x0)cos(x1)+1)/2

            const int w0 = slot * 4;
            float rr[4];
#pragma unroll
            for (int j = 0; j < 4; ++j) {
                const int w = w0 + j;  // word within the pair's 20 outputs
                const float q0 = fmaf(cx0, hc[w], fmaf(-sxx, hs[w], 0.5f));
                rr[j] = (w < C_CONST) ? q0 : q1v;
            }
            orow4[f] = make_float4(rr[0], rr[1], rr[2], rr[3]);
        }
    }
}

extern "C" void kernel_launch(void* const* d_in, const int* in_sizes, int n_in,
                              void* d_out, int out_size, void* d_ws, size_t ws_size,
                              hipStream_t stream) {
    const float* x     = (const float*)d_in[0];
    const int*   pidx  = (const int*)d_in[1];
    const float* theta = (const float*)d_in[2];
    float* out = (float*)d_out;

    quantum_pair_kernel<<<B_CONST, 256, 0, stream>>>(x, pidx, theta, out);
}